// Round 14
// baseline (533.897 us; speedup 1.0000x reference)
//
#include <hip/hip_runtime.h>
#include <cstdint>
#include <cstddef>

typedef unsigned short u16;
typedef __attribute__((ext_vector_type(8))) __bf16 bf16x8;
typedef __attribute__((ext_vector_type(4))) float f32x4;

#define MFMA(a, b, c) __builtin_amdgcn_mfma_f32_16x16x32_bf16(a, b, c, 0, 0, 0)

__device__ __forceinline__ u16 f2bf(float f) {
  union { float f; uint32_t u; } x; x.f = f;
  uint32_t r = x.u + 0x7fffu + ((x.u >> 16) & 1u);
  return (u16)(r >> 16);
}

__device__ __forceinline__ void gld16(const u16* g, u16* l) {
  __builtin_amdgcn_global_load_lds(
      (const __attribute__((address_space(1))) void*)g,
      (__attribute__((address_space(3))) void*)l, 16, 0, 0);
}

// ---------------- elementwise f32 -> bf16 convert ----------------
__global__ void cvt_f32_bf16(const float* __restrict__ src, u16* __restrict__ dst, int n4) {
  int i = blockIdx.x * blockDim.x + threadIdx.x;
  int stride = gridDim.x * blockDim.x;
  for (; i < n4; i += stride) {
    float4 v = ((const float4*)src)[i];
    ushort4 o;
    o.x = f2bf(v.x); o.y = f2bf(v.y); o.z = f2bf(v.z); o.w = f2bf(v.w);
    ((ushort4*)dst)[i] = o;
  }
}

// ---------------- merged prep: Wq/Wlin transpose+cvt (blocks 0..1151) + kv prep (1152..2687) ----------------
__global__ void prep_kern(const float* __restrict__ Wq, u16* __restrict__ wqt,
                          const float* __restrict__ Wlin, u16* __restrict__ wlt,
                          const float* __restrict__ bank, const float* __restrict__ Wkv,
                          const float* __restrict__ temp, u16* __restrict__ Kb,
                          u16* __restrict__ VT) {
  const int b = blockIdx.x;
  if (b < 1152) {
    __shared__ float tile[32][33];
    const float* src = (b >= 576) ? Wlin : Wq;
    u16* dst = (b >= 576) ? wlt : wqt;
    const int r = (b >= 576) ? b - 576 : b;
    const int bx = (r % 24) * 32, by = (r / 24) * 32;
    const int tx = threadIdx.x & 31, ty = threadIdx.x >> 5;
    #pragma unroll
    for (int i = ty; i < 32; i += 8)
      tile[i][tx] = src[(size_t)(by + i) * 768 + bx + tx];
    __syncthreads();
    #pragma unroll
    for (int i = ty; i < 32; i += 8)
      dst[(size_t)(bx + i) * 768 + by + tx] = f2bf(tile[tx][i]);
  } else {
    const int bb = b - 1152;                      // 0..1535
    const int h = bb >> 7;                        // 12 heads
    const int m = ((bb & 127) << 2) + (threadIdx.x >> 6);  // 4 waves = 4 bank rows
    const int j = threadIdx.x & 63;               // d index
    const float* br = bank + m * 16;
    float kj = 0.f, vj = 0.f;
    #pragma unroll
    for (int f = 0; f < 16; ++f) {
      float bv = br[f];
      kj = fmaf(bv, Wkv[f * 1536 + h * 64 + j], kj);
      vj = fmaf(bv, Wkv[f * 1536 + 768 + h * 64 + j], vj);
    }
    float ss = kj * kj;
    #pragma unroll
    for (int o = 32; o; o >>= 1) ss += __shfl_xor(ss, o);
    float rn = rsqrtf(fmaxf(ss, 1e-24f));
    Kb[((size_t)h * 512 + m) * 64 + j] = f2bf(kj * rn * temp[h] * 1.4426950408889634f);
    VT[((size_t)h * 64 + j) * 512 + m] = f2bf(vj);
  }
}

// ---------------- bf16 GEMM v3 (R6, verified), A (MxK) row-major, BT (NxK) row-major ----------------
// Counted-vmcnt 3-buffer pipeline (T4). Loop body per K-step:
//   s_waitcnt vmcnt(4)   -- own tile-k loads done (tile k+1's 4 still in flight)
//   s_barrier            -- raw: collective "everyone's tile-k staged"; NO vmcnt(0) drain
//   stage tile k+2       -- overwrites b[(k-1)%3]; safe: all waves read it pre-barrier
//   ds_read b[k%3]; MFMA
// R7 lesson: do NOT fuse f32 A staging here -- 2 blocks/CU + doubled ds_read + cvt on the
// fragment path = 2x regression. bf16 A via the separate cvt kernel is the verified form.
template <int MODE>
__global__ __launch_bounds__(256, 3) void gemm_bt(
    const u16* __restrict__ A, const u16* __restrict__ BT, void* __restrict__ Cout,
    int M, int N, int K, const float* __restrict__ bias, const float* __restrict__ prelu) {
  __shared__ u16 sA[3][128 * 32];
  __shared__ u16 sB[3][128 * 32];
  const int ntiles = N >> 7;
  const int swz = (blockIdx.x & 7) * (gridDim.x >> 3) + (blockIdx.x >> 3);
  const int m0 = (swz / ntiles) << 7;
  const int n0 = (swz % ntiles) << 7;
  const int tid = threadIdx.x;
  const int w = tid >> 6, lane = tid & 63;
  const int wm = (w >> 1) << 6, wn = (w & 1) << 6;
  const int srow = lane >> 2, scol = (lane & 3) << 3;
  const u16* ga = A + (size_t)(m0 + (w << 5) + srow) * K + scol;
  const u16* gb = BT + (size_t)(n0 + (w << 5) + srow) * K + scol;
  const int lofs = (w << 5) * 32;
  const int fr = lane & 15, fq = (lane >> 4) << 3;
  f32x4 acc[4][4] = {};

  auto stage = [&](int buf, int k0) {
    gld16(ga + k0, sA[buf] + lofs);
    gld16(ga + k0 + (size_t)16 * K, sA[buf] + lofs + 16 * 32);
    gld16(gb + k0, sB[buf] + lofs);
    gld16(gb + k0 + (size_t)16 * K, sB[buf] + lofs + 16 * 32);
  };

  const int nk = K >> 5;  // 24
  stage(0, 0);
  stage(1, 32);
  int cb = 0;   // buffer to read this iteration
  int sb = 2;   // buffer to stage this iteration (tile it+2)
  for (int it = 0; it < nk; ++it) {
    asm volatile("s_waitcnt vmcnt(4)\n\ts_barrier" ::: "memory");
    int nx = it + 2; if (nx >= nk) nx -= nk;   // wrap-stage keeps vmcnt uniform
    stage(sb, nx << 5);
    bf16x8 af[4], bfr[4];
    #pragma unroll
    for (int t = 0; t < 4; ++t) {
      af[t] = *(const bf16x8*)(sA[cb] + (wm + t * 16 + fr) * 32 + fq);
      bfr[t] = *(const bf16x8*)(sB[cb] + (wn + t * 16 + fr) * 32 + fq);
    }
    #pragma unroll
    for (int i = 0; i < 4; ++i)
      #pragma unroll
      for (int j = 0; j < 4; ++j)
        acc[i][j] = MFMA(af[i], bfr[j], acc[i][j]);
    cb = (cb == 2) ? 0 : cb + 1;
    sb = (sb == 2) ? 0 : sb + 1;
  }

  const int q = lane >> 4;
  float a = (MODE == 1) ? prelu[0] : 0.f;
  #pragma unroll
  for (int tm = 0; tm < 4; ++tm)
    #pragma unroll
    for (int tn = 0; tn < 4; ++tn) {
      int col = n0 + wn + tn * 16 + fr;
      float bv = (MODE == 1) ? bias[col] : 0.f;
      #pragma unroll
      for (int r = 0; r < 4; ++r) {
        int row = m0 + wm + tm * 16 + q * 4 + r;
        float v = acc[tm][tn][r];
        if (MODE == 1) {
          v += bv;
          v = v >= 0.f ? v : v * a;
          ((float*)Cout)[(size_t)row * N + col] = v;
        } else {
          ((u16*)Cout)[(size_t)row * N + col] = f2bf(v);
        }
      }
    }
}

// ---------------- fused cosine attention v4.2: 4-wave blocks (convoy-width halved) ----------------
// Same verified math/staging as v4.1 (R13, 71.5us): S^T = K·Q^T; PV consumes P directly
// from QK^T output regs via permuted key order + split-b64 V^T reads; reg-staged 64-key
// chunks, double-buffered. Restructure: 256 threads / 4 waves x 16 q-rows (g dimension
// removed), grid 6144. LDS still 36KB -> 4 independent blocks/CU (16 waves/CU, same as
// before) but barrier domain is 4 waves not 8, and 4 phase-shifted blocks fill each
// other's stalls (was 2). Regs drop to ~75/wave -> (256,4) cap 128, spill-safe.
// Extra K/V re-staging (4x block-chunks) is L2-resident (128KB/head): hbm_bytes ~flat.
// R9: no setprio. R11/R12: DMA staging closed. R5: don't regrow per-wave state.
__global__ __launch_bounds__(256, 4) void attn_kern(
    const u16* __restrict__ Q, const u16* __restrict__ Kb,
    const u16* __restrict__ Vt, u16* __restrict__ O) {
  __shared__ __align__(16) u16 sK[2][64 * 72];   // [chunk key][d + pad8]
  __shared__ __align__(16) u16 sV[2][64 * 72];   // [d][chunk key + pad8]

  const int qb = blockIdx.x & 511;
  const int h = blockIdx.x >> 9;
  const int tid = threadIdx.x, w = tid >> 6, lane = tid & 63;
  const int fr = lane & 15, quad = lane >> 4;
  const int row0 = qb * 64 + (w << 4) + fr;  // this lane's q-row

  // ---- load + normalize Q (B-operand layout: n=fr, k=quad*8+j) ----
  bf16x8 qa0, qa1;
  {
    const u16* qp = Q + (size_t)row0 * 768 + h * 64 + (quad << 3);
    qa0 = *(const bf16x8*)qp;
    qa1 = *(const bf16x8*)(qp + 32);
    float ss = 0.f;
    #pragma unroll
    for (int j = 0; j < 8; ++j) {
      float f0 = (float)qa0[j], f1 = (float)qa1[j];
      ss += f0 * f0 + f1 * f1;
    }
    ss += __shfl_xor(ss, 16);
    ss += __shfl_xor(ss, 32);
    float rn = rsqrtf(fmaxf(ss, 1e-24f));
    #pragma unroll
    for (int j = 0; j < 8; ++j) {
      qa0[j] = (__bf16)((float)qa0[j] * rn);
      qa1[j] = (__bf16)((float)qa1[j] * rn);
    }
  }

  // ---- staging: 64-key chunk = 8KB K + 8KB V; 256 threads x 2 x 16B each ----
  const u16* kg = Kb + (size_t)h * 512 * 64;
  const u16* vg = Vt + (size_t)h * 64 * 512;
  int4 kreg[2], vreg[2];
  auto load_chunk = [&](int c) {
    #pragma unroll
    for (int r = 0; r < 2; ++r) {
      int u = r * 256 + tid;
      kreg[r] = *(const int4*)(kg + (size_t)(c * 64 + (u >> 3)) * 64 + (u & 7) * 8);
      vreg[r] = *(const int4*)(vg + (size_t)(u >> 3) * 512 + c * 64 + (u & 7) * 8);
    }
  };
  auto store_chunk = [&](int buf) {
    #pragma unroll
    for (int r = 0; r < 2; ++r) {
      int u = r * 256 + tid;
      *(int4*)(sK[buf] + (u >> 3) * 72 + (u & 7) * 8) = kreg[r];
      *(int4*)(sV[buf] + (u >> 3) * 72 + (u & 7) * 8) = vreg[r];
    }
  };

  load_chunk(0);
  store_chunk(0);
  load_chunk(1);
  __syncthreads();

  f32x4 oa[4] = {};   // [d-tile] O^T accumulators
  f32x4 lsv = {};     // packed softmax-denominator partials

  for (int c = 0; c < 8; ++c) {
    const int cbuf = c & 1;
    // stage chunk c+1 (regs -> LDS other buffer), prefetch chunk c+2
    if (c < 7) store_chunk((c + 1) & 1);
    if (c < 6) load_chunk(c + 2);

    #pragma unroll
    for (int ks = 0; ks < 2; ++ks) {
      // ---- S^T = K . Q^T for key tiles mt = 2ks, 2ks+1 (32 keys) ----
      f32x4 s[2];  // [half]
      #pragma unroll
      for (int half = 0; half < 2; ++half) {
        const int mt = ks * 2 + half;
        const u16* kp = sK[cbuf] + (mt * 16 + fr) * 72 + (quad << 3);
        bf16x8 ak0 = *(const bf16x8*)kp;
        bf16x8 ak1 = *(const bf16x8*)(kp + 32);
        f32x4 z = {0.f, 0.f, 0.f, 0.f};
        z = MFMA(ak0, qa0, z);
        z = MFMA(ak1, qa1, z);
        s[half] = z;
      }
      // ---- exp2 (scores bounded; log2e*temp folded into K), denom, pack P in-reg ----
      bf16x8 pbf;
      #pragma unroll
      for (int half = 0; half < 2; ++half) {
        f32x4 pv;
        #pragma unroll
        for (int r = 0; r < 4; ++r) {
          pv[r] = __builtin_amdgcn_exp2f(s[half][r]);
          pbf[half * 4 + r] = (__bf16)pv[r];
        }
        lsv += pv;
      }
      // ---- PV: O^T += V^T . P^T with permuted key order (matches in-reg P layout) ----
      #pragma unroll
      for (int t = 0; t < 4; ++t) {
        const u16* vp = sV[cbuf] + (t * 16 + fr) * 72 + ks * 32 + (quad << 2);
        bf16x8 va;
        *(uint2*)&va = *(const uint2*)vp;              // keys 32ks + quad*4 + 0..3
        *((uint2*)&va + 1) = *(const uint2*)(vp + 16); // keys 32ks + 16 + quad*4 + 0..3
        oa[t] = MFMA(va, pbf, oa[t]);
      }
    }
    __syncthreads();
  }

  // ---- epilogue: reduce denominators across quads, scale, store ----
  {
    float l = lsv[0] + lsv[1] + lsv[2] + lsv[3];
    l += __shfl_xor(l, 16);
    l += __shfl_xor(l, 32);
    float rl = __builtin_amdgcn_rcpf(l);
    u16* op = O + (size_t)row0 * 768 + h * 64 + (quad << 2);
    #pragma unroll
    for (int t = 0; t < 4; ++t) {
      ushort4 pk;
      pk.x = f2bf(oa[t][0] * rl);
      pk.y = f2bf(oa[t][1] * rl);
      pk.z = f2bf(oa[t][2] * rl);
      pk.w = f2bf(oa[t][3] * rl);
      *(ushort4*)(op + t * 16) = pk;
    }
  }
}

extern "C" void kernel_launch(void* const* d_in, const int* in_sizes, int n_in,
                              void* d_out, int out_size, void* d_ws, size_t ws_size,
                              hipStream_t stream) {
  const float* x      = (const float*)d_in[0];  // (8,4096,768)
  const float* bank   = (const float*)d_in[1];  // (1,512,16)
  const float* Wq     = (const float*)d_in[2];  // (768,768)
  const float* Wkv    = (const float*)d_in[3];  // (16,1536)
  const float* Wlin   = (const float*)d_in[4];  // (768,768)
  const float* b_lin  = (const float*)d_in[5];  // (768,)
  const float* prelu  = (const float*)d_in[6];  // scalar
  const float* temp   = (const float*)d_in[7];  // (12,1,1)
  float* out = (float*)d_out;

  char* ws = (char*)d_ws;
  const size_t NELEM = 25165824;  // 8*4096*768
  u16* qbuf  = (u16*)ws;                          // bf16 q
  u16* xbuf  = (u16*)(ws + 50331648);             // x bf16; aliased as O after GEMM1
  u16* obuf  = xbuf;
  u16* wqt   = (u16*)(ws + 100663296);
  u16* wlt   = wqt + 589824;
  u16* kbuf  = wlt + 589824;
  u16* vtbuf = kbuf + 393216;

  prep_kern<<<2688, 256, 0, stream>>>(Wq, wqt, Wlin, wlt, bank, Wkv, temp, kbuf, vtbuf);
  cvt_f32_bf16<<<4096, 256, 0, stream>>>(x, xbuf, (int)(NELEM / 4));
  gemm_bt<0><<<1536, 256, 0, stream>>>(xbuf, wqt, qbuf, 32768, 768, 768, nullptr, nullptr);
  attn_kern<<<6144, 256, 0, stream>>>(qbuf, kbuf, vtbuf, obuf);
  gemm_bt<1><<<1536, 256, 0, stream>>>(obuf, wlt, out, 32768, 768, 768, b_lin, prelu);
}

// Round 15
// 355.275 us; speedup vs baseline: 1.5028x; 1.5028x over previous
//
#include <hip/hip_runtime.h>
#include <cstdint>
#include <cstddef>

typedef unsigned short u16;
typedef __attribute__((ext_vector_type(8))) __bf16 bf16x8;
typedef __attribute__((ext_vector_type(4))) float f32x4;

#define MFMA(a, b, c) __builtin_amdgcn_mfma_f32_16x16x32_bf16(a, b, c, 0, 0, 0)

__device__ __forceinline__ u16 f2bf(float f) {
  union { float f; uint32_t u; } x; x.f = f;
  uint32_t r = x.u + 0x7fffu + ((x.u >> 16) & 1u);
  return (u16)(r >> 16);
}

__device__ __forceinline__ void gld16(const u16* g, u16* l) {
  __builtin_amdgcn_global_load_lds(
      (const __attribute__((address_space(1))) void*)g,
      (__attribute__((address_space(3))) void*)l, 16, 0, 0);
}

// ---------------- elementwise f32 -> bf16 convert ----------------
__global__ void cvt_f32_bf16(const float* __restrict__ src, u16* __restrict__ dst, int n4) {
  int i = blockIdx.x * blockDim.x + threadIdx.x;
  int stride = gridDim.x * blockDim.x;
  for (; i < n4; i += stride) {
    float4 v = ((const float4*)src)[i];
    ushort4 o;
    o.x = f2bf(v.x); o.y = f2bf(v.y); o.z = f2bf(v.z); o.w = f2bf(v.w);
    ((ushort4*)dst)[i] = o;
  }
}

// ---------------- merged prep: Wq/Wlin transpose+cvt (blocks 0..1151) + kv prep (1152..2687) ----------------
__global__ void prep_kern(const float* __restrict__ Wq, u16* __restrict__ wqt,
                          const float* __restrict__ Wlin, u16* __restrict__ wlt,
                          const float* __restrict__ bank, const float* __restrict__ Wkv,
                          const float* __restrict__ temp, u16* __restrict__ Kb,
                          u16* __restrict__ VT) {
  const int b = blockIdx.x;
  if (b < 1152) {
    __shared__ float tile[32][33];
    const float* src = (b >= 576) ? Wlin : Wq;
    u16* dst = (b >= 576) ? wlt : wqt;
    const int r = (b >= 576) ? b - 576 : b;
    const int bx = (r % 24) * 32, by = (r / 24) * 32;
    const int tx = threadIdx.x & 31, ty = threadIdx.x >> 5;
    #pragma unroll
    for (int i = ty; i < 32; i += 8)
      tile[i][tx] = src[(size_t)(by + i) * 768 + bx + tx];
    __syncthreads();
    #pragma unroll
    for (int i = ty; i < 32; i += 8)
      dst[(size_t)(bx + i) * 768 + by + tx] = f2bf(tile[tx][i]);
  } else {
    const int bb = b - 1152;                      // 0..1535
    const int h = bb >> 7;                        // 12 heads
    const int m = ((bb & 127) << 2) + (threadIdx.x >> 6);  // 4 waves = 4 bank rows
    const int j = threadIdx.x & 63;               // d index
    const float* br = bank + m * 16;
    float kj = 0.f, vj = 0.f;
    #pragma unroll
    for (int f = 0; f < 16; ++f) {
      float bv = br[f];
      kj = fmaf(bv, Wkv[f * 1536 + h * 64 + j], kj);
      vj = fmaf(bv, Wkv[f * 1536 + 768 + h * 64 + j], vj);
    }
    float ss = kj * kj;
    #pragma unroll
    for (int o = 32; o; o >>= 1) ss += __shfl_xor(ss, o);
    float rn = rsqrtf(fmaxf(ss, 1e-24f));
    Kb[((size_t)h * 512 + m) * 64 + j] = f2bf(kj * rn * temp[h] * 1.4426950408889634f);
    VT[((size_t)h * 64 + j) * 512 + m] = f2bf(vj);
  }
}

// ---------------- bf16 GEMM v3 (R6, verified), A (MxK) row-major, BT (NxK) row-major ----------------
// Counted-vmcnt 3-buffer pipeline (T4). Loop body per K-step:
//   s_waitcnt vmcnt(4)   -- own tile-k loads done (tile k+1's 4 still in flight)
//   s_barrier            -- raw: collective "everyone's tile-k staged"; NO vmcnt(0) drain
//   stage tile k+2       -- overwrites b[(k-1)%3]; safe: all waves read it pre-barrier
//   ds_read b[k%3]; MFMA
// R7 lesson: do NOT fuse f32 A staging here -- 2 blocks/CU + doubled ds_read + cvt on the
// fragment path = 2x regression. bf16 A via the separate cvt kernel is the verified form.
template <int MODE>
__global__ __launch_bounds__(256, 3) void gemm_bt(
    const u16* __restrict__ A, const u16* __restrict__ BT, void* __restrict__ Cout,
    int M, int N, int K, const float* __restrict__ bias, const float* __restrict__ prelu) {
  __shared__ u16 sA[3][128 * 32];
  __shared__ u16 sB[3][128 * 32];
  const int ntiles = N >> 7;
  const int swz = (blockIdx.x & 7) * (gridDim.x >> 3) + (blockIdx.x >> 3);
  const int m0 = (swz / ntiles) << 7;
  const int n0 = (swz % ntiles) << 7;
  const int tid = threadIdx.x;
  const int w = tid >> 6, lane = tid & 63;
  const int wm = (w >> 1) << 6, wn = (w & 1) << 6;
  const int srow = lane >> 2, scol = (lane & 3) << 3;
  const u16* ga = A + (size_t)(m0 + (w << 5) + srow) * K + scol;
  const u16* gb = BT + (size_t)(n0 + (w << 5) + srow) * K + scol;
  const int lofs = (w << 5) * 32;
  const int fr = lane & 15, fq = (lane >> 4) << 3;
  f32x4 acc[4][4] = {};

  auto stage = [&](int buf, int k0) {
    gld16(ga + k0, sA[buf] + lofs);
    gld16(ga + k0 + (size_t)16 * K, sA[buf] + lofs + 16 * 32);
    gld16(gb + k0, sB[buf] + lofs);
    gld16(gb + k0 + (size_t)16 * K, sB[buf] + lofs + 16 * 32);
  };

  const int nk = K >> 5;  // 24
  stage(0, 0);
  stage(1, 32);
  int cb = 0;   // buffer to read this iteration
  int sb = 2;   // buffer to stage this iteration (tile it+2)
  for (int it = 0; it < nk; ++it) {
    asm volatile("s_waitcnt vmcnt(4)\n\ts_barrier" ::: "memory");
    int nx = it + 2; if (nx >= nk) nx -= nk;   // wrap-stage keeps vmcnt uniform
    stage(sb, nx << 5);
    bf16x8 af[4], bfr[4];
    #pragma unroll
    for (int t = 0; t < 4; ++t) {
      af[t] = *(const bf16x8*)(sA[cb] + (wm + t * 16 + fr) * 32 + fq);
      bfr[t] = *(const bf16x8*)(sB[cb] + (wn + t * 16 + fr) * 32 + fq);
    }
    #pragma unroll
    for (int i = 0; i < 4; ++i)
      #pragma unroll
      for (int j = 0; j < 4; ++j)
        acc[i][j] = MFMA(af[i], bfr[j], acc[i][j]);
    cb = (cb == 2) ? 0 : cb + 1;
    sb = (sb == 2) ? 0 : sb + 1;
  }

  const int q = lane >> 4;
  float a = (MODE == 1) ? prelu[0] : 0.f;
  #pragma unroll
  for (int tm = 0; tm < 4; ++tm)
    #pragma unroll
    for (int tn = 0; tn < 4; ++tn) {
      int col = n0 + wn + tn * 16 + fr;
      float bv = (MODE == 1) ? bias[col] : 0.f;
      #pragma unroll
      for (int r = 0; r < 4; ++r) {
        int row = m0 + wm + tm * 16 + q * 4 + r;
        float v = acc[tm][tn][r];
        if (MODE == 1) {
          v += bv;
          v = v >= 0.f ? v : v * a;
          ((float*)Cout)[(size_t)row * N + col] = v;
        } else {
          ((u16*)Cout)[(size_t)row * N + col] = f2bf(v);
        }
      }
    }
}

// ---------------- fused cosine attention v4.1 (R13-verified 71.5us, byte-identical revert) ----------------
// Exact v4 structure: S^T = K·Q^T; PV consumes P directly from QK^T output regs via
// permuted key order matched by split-b64 V^T reads. 8 waves x 32 q-rows, 64-key chunks
// double-buffered through regs. Packed f32x4 denominator.
// CLOSED levers (do not reopen): R5 128-key chunks (spill); R9 setprio (lockstep waves);
// R11/R12 DMA staging (container-killing); R14 4-wave geometry (13x traffic explosion --
// block-geometry changes defeat the register-estimate model; R1 same signature).
__global__ __launch_bounds__(512, 4) void attn_kern(
    const u16* __restrict__ Q, const u16* __restrict__ Kb,
    const u16* __restrict__ Vt, u16* __restrict__ O) {
  __shared__ __align__(16) u16 sK[2][64 * 72];   // [chunk key][d + pad8]
  __shared__ __align__(16) u16 sV[2][64 * 72];   // [d][chunk key + pad8]

  const int qb = blockIdx.x & 127;
  const int h = blockIdx.x >> 7;
  const int tid = threadIdx.x, w = tid >> 6, lane = tid & 63;
  const int fr = lane & 15, quad = lane >> 4;
  const int rowbase = qb * 256 + (w << 5);  // 8 waves x 32 rows

  // ---- load + normalize Q for 2 row-groups (B-operand layout: n=fr, k=quad*8+j) ----
  bf16x8 qa[2][2];
  #pragma unroll
  for (int g = 0; g < 2; ++g) {
    const u16* qp = Q + (size_t)(rowbase + g * 16 + fr) * 768 + h * 64 + (quad << 3);
    qa[g][0] = *(const bf16x8*)qp;
    qa[g][1] = *(const bf16x8*)(qp + 32);
    float ss = 0.f;
    #pragma unroll
    for (int j = 0; j < 8; ++j) {
      float f0 = (float)qa[g][0][j], f1 = (float)qa[g][1][j];
      ss += f0 * f0 + f1 * f1;
    }
    ss += __shfl_xor(ss, 16);
    ss += __shfl_xor(ss, 32);
    float rn = rsqrtf(fmaxf(ss, 1e-24f));
    #pragma unroll
    for (int j = 0; j < 8; ++j) {
      qa[g][0][j] = (__bf16)((float)qa[g][0][j] * rn);
      qa[g][1][j] = (__bf16)((float)qa[g][1][j] * rn);
    }
  }

  // ---- staging: 64-key chunk = 8KB K + 8KB V; 512 threads x 1 x 16B each ----
  const u16* kg = Kb + (size_t)h * 512 * 64;
  const u16* vg = Vt + (size_t)h * 64 * 512;
  int4 kreg, vreg;
  auto load_chunk = [&](int c) {
    kreg = *(const int4*)(kg + (size_t)(c * 64 + (tid >> 3)) * 64 + (tid & 7) * 8);
    vreg = *(const int4*)(vg + (size_t)(tid >> 3) * 512 + c * 64 + (tid & 7) * 8);
  };
  auto store_chunk = [&](int buf) {
    *(int4*)(sK[buf] + (tid >> 3) * 72 + (tid & 7) * 8) = kreg;
    *(int4*)(sV[buf] + (tid >> 3) * 72 + (tid & 7) * 8) = vreg;
  };

  load_chunk(0);
  store_chunk(0);
  load_chunk(1);
  __syncthreads();

  f32x4 oa[2][4] = {};   // [g][d-tile] O^T accumulators
  f32x4 lsv[2] = {};     // packed softmax-denominator partials per group

  for (int c = 0; c < 8; ++c) {
    const int cb = c & 1;
    // stage chunk c+1 (regs -> LDS other buffer), prefetch chunk c+2
    if (c < 7) store_chunk((c + 1) & 1);
    if (c < 6) load_chunk(c + 2);

    #pragma unroll
    for (int ks = 0; ks < 2; ++ks) {
      // ---- S^T = K . Q^T for key tiles mt = 2ks, 2ks+1 (32 keys) ----
      f32x4 s[2][2];  // [g][half]
      #pragma unroll
      for (int half = 0; half < 2; ++half) {
        const int mt = ks * 2 + half;
        const u16* kp = sK[cb] + (mt * 16 + fr) * 72 + (quad << 3);
        bf16x8 ak0 = *(const bf16x8*)kp;
        bf16x8 ak1 = *(const bf16x8*)(kp + 32);
        #pragma unroll
        for (int g = 0; g < 2; ++g) {
          f32x4 z = {0.f, 0.f, 0.f, 0.f};
          z = MFMA(ak0, qa[g][0], z);
          z = MFMA(ak1, qa[g][1], z);
          s[g][half] = z;
        }
      }
      // ---- exp2 (scores bounded; log2e*temp folded into K), denom, pack P in-reg ----
      bf16x8 pbf[2];
      #pragma unroll
      for (int g = 0; g < 2; ++g)
        #pragma unroll
        for (int half = 0; half < 2; ++half) {
          f32x4 pv;
          #pragma unroll
          for (int r = 0; r < 4; ++r) {
            pv[r] = __builtin_amdgcn_exp2f(s[g][half][r]);
            pbf[g][half * 4 + r] = (__bf16)pv[r];
          }
          lsv[g] += pv;
        }
      // ---- PV: O^T += V^T . P^T with permuted key order (matches in-reg P layout) ----
      #pragma unroll
      for (int t = 0; t < 4; ++t) {
        const u16* vp = sV[cb] + (t * 16 + fr) * 72 + ks * 32 + (quad << 2);
        bf16x8 va;
        *(uint2*)&va = *(const uint2*)vp;              // keys 32ks + quad*4 + 0..3
        *((uint2*)&va + 1) = *(const uint2*)(vp + 16); // keys 32ks + 16 + quad*4 + 0..3
        #pragma unroll
        for (int g = 0; g < 2; ++g)
          oa[g][t] = MFMA(va, pbf[g], oa[g][t]);
      }
    }
    __syncthreads();
  }

  // ---- epilogue: reduce denominators across quads, scale, store ----
  #pragma unroll
  for (int g = 0; g < 2; ++g) {
    float l = lsv[g][0] + lsv[g][1] + lsv[g][2] + lsv[g][3];
    l += __shfl_xor(l, 16);
    l += __shfl_xor(l, 32);
    float rl = __builtin_amdgcn_rcpf(l);
    u16* op = O + (size_t)(rowbase + g * 16 + fr) * 768 + h * 64 + (quad << 2);
    #pragma unroll
    for (int t = 0; t < 4; ++t) {
      ushort4 pk;
      pk.x = f2bf(oa[g][t][0] * rl);
      pk.y = f2bf(oa[g][t][1] * rl);
      pk.z = f2bf(oa[g][t][2] * rl);
      pk.w = f2bf(oa[g][t][3] * rl);
      *(ushort4*)(op + t * 16) = pk;
    }
  }
}

extern "C" void kernel_launch(void* const* d_in, const int* in_sizes, int n_in,
                              void* d_out, int out_size, void* d_ws, size_t ws_size,
                              hipStream_t stream) {
  const float* x      = (const float*)d_in[0];  // (8,4096,768)
  const float* bank   = (const float*)d_in[1];  // (1,512,16)
  const float* Wq     = (const float*)d_in[2];  // (768,768)
  const float* Wkv    = (const float*)d_in[3];  // (16,1536)
  const float* Wlin   = (const float*)d_in[4];  // (768,768)
  const float* b_lin  = (const float*)d_in[5];  // (768,)
  const float* prelu  = (const float*)d_in[6];  // scalar
  const float* temp   = (const float*)d_in[7];  // (12,1,1)
  float* out = (float*)d_out;

  char* ws = (char*)d_ws;
  const size_t NELEM = 25165824;  // 8*4096*768
  u16* qbuf  = (u16*)ws;                          // bf16 q
  u16* xbuf  = (u16*)(ws + 50331648);             // x bf16; aliased as O after GEMM1
  u16* obuf  = xbuf;
  u16* wqt   = (u16*)(ws + 100663296);
  u16* wlt   = wqt + 589824;
  u16* kbuf  = wlt + 589824;
  u16* vtbuf = kbuf + 393216;

  prep_kern<<<2688, 256, 0, stream>>>(Wq, wqt, Wlin, wlt, bank, Wkv, temp, kbuf, vtbuf);
  cvt_f32_bf16<<<4096, 256, 0, stream>>>(x, xbuf, (int)(NELEM / 4));
  gemm_bt<0><<<1536, 256, 0, stream>>>(xbuf, wqt, qbuf, 32768, 768, 768, nullptr, nullptr);
  attn_kern<<<1536, 512, 0, stream>>>(qbuf, kbuf, vtbuf, obuf);
  gemm_bt<1><<<1536, 256, 0, stream>>>(obuf, wlt, out, 32768, 768, 768, b_lin, prelu);
}